// Round 4
// baseline (24059.630 us; speedup 1.0000x reference)
//
#include <hip/hip_runtime.h>
#include <hip/hip_bf16.h>

#define S_DIM 128
#define H_DIM 256
#define A_DIM 8
#define T_STEPS 16
#define BT 8            // batch elements per block
#define HP 264          // padded row length for f32 LDS tiles

// 512 threads: tid = (h<<8) | n ; n = neuron 0..255, h = j-half (0..1).
// Each thread holds W2[n][128h .. 128h+128) in 128 VGPRs (32 float4).
// LIF state (h1,v1,v2) lives on h==0 threads. All accumulation in f64 to
// match the float-accurate numpy reference (f32 products are exact in f64).
// OUTPUT IS FLOAT32 (reference returns jnp.float32).
__global__ __launch_bounds__(512, 2)
void snn_actor_f64(const float* __restrict__ state,
                   const float* __restrict__ W1, const float* __restrict__ b1,
                   const float* __restrict__ W2, const float* __restrict__ b2,
                   const float* __restrict__ W3, const float* __restrict__ b3,
                   float* __restrict__ out)
{
    __shared__ alignas(16) float  st[BT][S_DIM];     // 4 KB state tile
    __shared__ alignas(16) float  s1s[BT][HP];       // 8.25 KB spikes L1
    __shared__ alignas(16) float  s2s[BT][HP];       // 8.25 KB spikes L2
    __shared__ alignas(16) float  w3s[A_DIM][HP];    // 8.25 KB W3 staged
    __shared__ double redh[BT][H_DIM];               // 16 KB h2/h1 partials (h==1 half)
    __shared__ double red3[8][64];                   // 4 KB  h3 chunk partials
    __shared__ unsigned int msk[BT][8];              // 256 B spike bitmasks

    const int tid = threadIdx.x;
    const int n   = tid & 255;
    const int h   = tid >> 8;
    const long b0 = (long)blockIdx.x * BT;

    // ---- stage state tile (1024 f32 = 256 float4) ----
    if (tid < 256) {
        reinterpret_cast<float4*>(&st[0][0])[tid] =
            reinterpret_cast<const float4*>(state + b0 * S_DIM)[tid];
    }
    // ---- stage W3 (2048 f32 = 512 float4; one per thread) ----
    {
        const int a = tid >> 6, c = tid & 63;
        reinterpret_cast<float4*>(&w3s[a][0])[c] =
            reinterpret_cast<const float4*>(W3)[tid];
    }
    __syncthreads();

    // ---- W2 half-row into registers (32 float4 = 128 VGPR) ----
    float4 w2r[32];
    {
        const float4* w2p = reinterpret_cast<const float4*>(W2 + n * H_DIM + h * 128);
        #pragma unroll
        for (int q = 0; q < 32; ++q) w2r[q] = w2p[q];
    }

    // ---- h1 = state @ W1^T + b1 in f64, split by k-half ----
    double hacc[BT];
    #pragma unroll
    for (int bt = 0; bt < BT; ++bt) hacc[bt] = 0.0;
    {
        const float* w1p = W1 + n * S_DIM + h * 64;
        for (int kq = 0; kq < 16; ++kq) {
            float4 w4 = reinterpret_cast<const float4*>(w1p)[kq];
            const double wd0 = (double)w4.x, wd1 = (double)w4.y;
            const double wd2 = (double)w4.z, wd3 = (double)w4.w;
            #pragma unroll
            for (int bt = 0; bt < BT; ++bt) {
                float4 s4 = *reinterpret_cast<const float4*>(&st[bt][h * 64 + kq * 4]);
                double a = hacc[bt];
                a = fma(wd0, (double)s4.x, a);
                a = fma(wd1, (double)s4.y, a);
                a = fma(wd2, (double)s4.z, a);
                a = fma(wd3, (double)s4.w, a);
                hacc[bt] = a;
            }
        }
    }
    if (h) {
        #pragma unroll
        for (int bt = 0; bt < BT; ++bt) redh[bt][n] = hacc[bt];
    }
    __syncthreads();

    double h1r[BT], v1r[BT], v2r[BT];
    const double b2d = h ? 0.0 : (double)b2[n];
    if (!h) {
        const double b1d = (double)b1[n];
        #pragma unroll
        for (int bt = 0; bt < BT; ++bt) {
            h1r[bt] = hacc[bt] + redh[bt][n] + b1d;
            v1r[bt] = 0.0;
            v2r[bt] = 0.0;
        }
    } else {
        #pragma unroll
        for (int bt = 0; bt < BT; ++bt) { h1r[bt] = 0.0; v1r[bt] = 0.0; v2r[bt] = 0.0; }
    }

    // h3 task mapping (threads cooperate 8-way over j)
    const int task  = tid & 63;          // (bt,a)
    const int chunk = tid >> 6;          // j-chunk 0..7 (32 j each)
    const int hbt = task >> 3, ha = task & 7;
    const double b3d = (double)b3[ha];
    double v3r = 0.0;

    for (int t = 0; t < T_STEPS; ++t) {
        // ---- LIF layer 1 (h==0 threads own neurons), spikes + bitmask ----
        if (!h) {
            #pragma unroll
            for (int bt = 0; bt < BT; ++bt) {
                double v = v1r[bt];
                v = v + (h1r[bt] - v) * 0.5;
                const bool sp = (v >= 1.0);
                v1r[bt] = sp ? 0.0 : v;
                s1s[bt][n] = sp ? 1.0f : 0.0f;
                unsigned long long bal = __ballot(sp);
                if ((n & 63) == 0) {
                    const int w = n >> 6;
                    msk[bt][2 * w]     = (unsigned int)bal;
                    msk[bt][2 * w + 1] = (unsigned int)(bal >> 32);
                }
            }
        }
        __syncthreads();

        // ---- h2 partial: thread's 128-j half, skip all-zero spike quads ----
        double acc[BT];
        #pragma unroll
        for (int bt = 0; bt < BT; ++bt) acc[bt] = 0.0;

        unsigned int mm[BT][4];
        #pragma unroll
        for (int bt = 0; bt < BT; ++bt) {
            #pragma unroll
            for (int w = 0; w < 4; ++w)
                mm[bt][w] = __builtin_amdgcn_readfirstlane(msk[bt][4 * h + w]);
        }

        const int jbase = h * 128;
        #pragma unroll
        for (int q = 0; q < 32; ++q) {
            const float4 w4 = w2r[q];
            const double wd0 = (double)w4.x, wd1 = (double)w4.y;
            const double wd2 = (double)w4.z, wd3 = (double)w4.w;
            #pragma unroll
            for (int bt = 0; bt < BT; ++bt) {
                if ((mm[bt][q >> 3] >> ((q & 7) * 4)) & 15u) {   // uniform -> s_cbranch
                    float4 s4 = *reinterpret_cast<const float4*>(&s1s[bt][jbase + q * 4]);
                    double a = acc[bt];
                    a = fma(wd0, (double)s4.x, a);
                    a = fma(wd1, (double)s4.y, a);
                    a = fma(wd2, (double)s4.z, a);
                    a = fma(wd3, (double)s4.w, a);
                    acc[bt] = a;
                }
            }
        }
        if (h) {
            #pragma unroll
            for (int bt = 0; bt < BT; ++bt) redh[bt][n] = acc[bt];
        }
        __syncthreads();

        // ---- LIF layer 2 on h==0 ----
        if (!h) {
            #pragma unroll
            for (int bt = 0; bt < BT; ++bt) {
                const double h2 = acc[bt] + redh[bt][n] + b2d;
                double v = v2r[bt];
                v = v + (h2 - v) * 0.5;
                const bool sp = (v >= 1.0);
                v2r[bt] = sp ? 0.0 : v;
                s2s[bt][n] = sp ? 1.0f : 0.0f;
            }
        }
        __syncthreads();

        // ---- h3 = s2 @ W3^T: 512 threads = 64 tasks x 8 j-chunks ----
        {
            double a3 = 0.0;
            const int j0 = chunk * 32;
            #pragma unroll
            for (int q = 0; q < 8; ++q) {
                float4 w4 = *reinterpret_cast<const float4*>(&w3s[ha][j0 + q * 4]);
                float4 s4 = *reinterpret_cast<const float4*>(&s2s[hbt][j0 + q * 4]);
                a3 = fma((double)w4.x, (double)s4.x, a3);
                a3 = fma((double)w4.y, (double)s4.y, a3);
                a3 = fma((double)w4.z, (double)s4.z, a3);
                a3 = fma((double)w4.w, (double)s4.w, a3);
            }
            red3[chunk][task] = a3;
        }
        __syncthreads();

        // ---- non-spiking integrate on threads 0..63 ----
        if (tid < 64) {
            const double h3 = ((red3[0][task] + red3[1][task]) + (red3[2][task] + red3[3][task]))
                            + ((red3[4][task] + red3[5][task]) + (red3[6][task] + red3[7][task]))
                            + b3d;
            double v = v3r;
            v = v + (h3 - v) * 0.5;
            v3r = v;
        }
    }

    // ---- output: tanh(v3) -> FLOAT32 ----
    if (tid < 64) {
        out[(b0 + hbt) * A_DIM + ha] = (float)tanh(v3r);
    }
}

extern "C" void kernel_launch(void* const* d_in, const int* in_sizes, int n_in,
                              void* d_out, int out_size, void* d_ws, size_t ws_size,
                              hipStream_t stream)
{
    const float* state = (const float*)d_in[0];
    const float* W1    = (const float*)d_in[1];
    const float* b1    = (const float*)d_in[2];
    const float* W2    = (const float*)d_in[3];
    const float* b2    = (const float*)d_in[4];
    const float* W3    = (const float*)d_in[5];
    const float* b3    = (const float*)d_in[6];
    float* out = (float*)d_out;

    const int B = in_sizes[0] / S_DIM;      // 131072
    const int grid = B / BT;                // 16384

    snn_actor_f64<<<grid, 512, 0, stream>>>(state, W1, b1, W2, b2, W3, b3, out);
}

// Round 5
// 24039.986 us; speedup vs baseline: 1.0008x; 1.0008x over previous
//
#include <hip/hip_runtime.h>
#include <hip/hip_bf16.h>

#define S_DIM 128
#define H_DIM 256
#define A_DIM 8
#define T_STEPS 16
#define BT 8            // batch elements per block
#define HP 264          // padded row length for f32 LDS tiles

// 512 threads: tid = (h<<8) | n ; n = neuron 0..255, h = j-half (0..1).
// Each thread holds W2[n][128h .. 128h+128) in 128 VGPRs (32 float4).
// LIF state (h1,v1,v2) lives on h==0 threads. All accumulation in f64 to
// match the float-accurate numpy reference (f32 products are exact in f64).
// OUTPUT IS FLOAT32 (reference returns jnp.float32).
__global__ __launch_bounds__(512, 2)
void snn_actor_f64(const float* __restrict__ state,
                   const float* __restrict__ W1, const float* __restrict__ b1,
                   const float* __restrict__ W2, const float* __restrict__ b2,
                   const float* __restrict__ W3, const float* __restrict__ b3,
                   float* __restrict__ out)
{
    __shared__ alignas(16) float  st[BT][S_DIM];     // 4 KB state tile
    __shared__ alignas(16) float  s1s[BT][HP];       // 8.25 KB spikes L1
    __shared__ alignas(16) float  s2s[BT][HP];       // 8.25 KB spikes L2
    __shared__ alignas(16) float  w3s[A_DIM][HP];    // 8.25 KB W3 staged
    __shared__ double redh[BT][H_DIM];               // 16 KB h2/h1 partials (h==1 half)
    __shared__ double red3[8][64];                   // 4 KB  h3 chunk partials
    __shared__ unsigned int msk[BT][8];              // 256 B spike bitmasks

    const int tid = threadIdx.x;
    const int n   = tid & 255;
    const int h   = tid >> 8;
    const long b0 = (long)blockIdx.x * BT;

    // ---- stage state tile (1024 f32 = 256 float4) ----
    if (tid < 256) {
        reinterpret_cast<float4*>(&st[0][0])[tid] =
            reinterpret_cast<const float4*>(state + b0 * S_DIM)[tid];
    }
    // ---- stage W3 (2048 f32 = 512 float4; one per thread) ----
    {
        const int a = tid >> 6, c = tid & 63;
        reinterpret_cast<float4*>(&w3s[a][0])[c] =
            reinterpret_cast<const float4*>(W3)[tid];
    }
    __syncthreads();

    // ---- W2 half-row into registers (32 float4 = 128 VGPR) ----
    float4 w2r[32];
    {
        const float4* w2p = reinterpret_cast<const float4*>(W2 + n * H_DIM + h * 128);
        #pragma unroll
        for (int q = 0; q < 32; ++q) w2r[q] = w2p[q];
    }

    // ---- h1 = state @ W1^T + b1 in f64, split by k-half ----
    double hacc[BT];
    #pragma unroll
    for (int bt = 0; bt < BT; ++bt) hacc[bt] = 0.0;
    {
        const float* w1p = W1 + n * S_DIM + h * 64;
        for (int kq = 0; kq < 16; ++kq) {
            float4 w4 = reinterpret_cast<const float4*>(w1p)[kq];
            const double wd0 = (double)w4.x, wd1 = (double)w4.y;
            const double wd2 = (double)w4.z, wd3 = (double)w4.w;
            #pragma unroll
            for (int bt = 0; bt < BT; ++bt) {
                float4 s4 = *reinterpret_cast<const float4*>(&st[bt][h * 64 + kq * 4]);
                double a = hacc[bt];
                a = fma(wd0, (double)s4.x, a);
                a = fma(wd1, (double)s4.y, a);
                a = fma(wd2, (double)s4.z, a);
                a = fma(wd3, (double)s4.w, a);
                hacc[bt] = a;
            }
        }
    }
    if (h) {
        #pragma unroll
        for (int bt = 0; bt < BT; ++bt) redh[bt][n] = hacc[bt];
    }
    __syncthreads();

    double h1r[BT], v1r[BT], v2r[BT];
    const double b2d = h ? 0.0 : (double)b2[n];
    if (!h) {
        const double b1d = (double)b1[n];
        #pragma unroll
        for (int bt = 0; bt < BT; ++bt) {
            h1r[bt] = hacc[bt] + redh[bt][n] + b1d;
            v1r[bt] = 0.0;
            v2r[bt] = 0.0;
        }
    } else {
        #pragma unroll
        for (int bt = 0; bt < BT; ++bt) { h1r[bt] = 0.0; v1r[bt] = 0.0; v2r[bt] = 0.0; }
    }

    // h3 task mapping (threads cooperate 8-way over j)
    const int task  = tid & 63;          // (bt,a)
    const int chunk = tid >> 6;          // j-chunk 0..7 (32 j each)
    const int hbt = task >> 3, ha = task & 7;
    const double b3d = (double)b3[ha];
    double v3r = 0.0;

    for (int t = 0; t < T_STEPS; ++t) {
        // ---- LIF layer 1 (h==0 threads own neurons), spikes + bitmask ----
        if (!h) {
            #pragma unroll
            for (int bt = 0; bt < BT; ++bt) {
                double v = v1r[bt];
                v = v + (h1r[bt] - v) * 0.5;
                const bool sp = (v >= 1.0);
                v1r[bt] = sp ? 0.0 : v;
                s1s[bt][n] = sp ? 1.0f : 0.0f;
                unsigned long long bal = __ballot(sp);
                if ((n & 63) == 0) {
                    const int w = n >> 6;
                    msk[bt][2 * w]     = (unsigned int)bal;
                    msk[bt][2 * w + 1] = (unsigned int)(bal >> 32);
                }
            }
        }
        __syncthreads();

        // ---- h2 partial: thread's 128-j half, skip all-zero spike quads ----
        double acc[BT];
        #pragma unroll
        for (int bt = 0; bt < BT; ++bt) acc[bt] = 0.0;

        unsigned int mm[BT][4];
        #pragma unroll
        for (int bt = 0; bt < BT; ++bt) {
            #pragma unroll
            for (int w = 0; w < 4; ++w)
                mm[bt][w] = __builtin_amdgcn_readfirstlane(msk[bt][4 * h + w]);
        }

        const int jbase = h * 128;
        #pragma unroll
        for (int q = 0; q < 32; ++q) {
            const float4 w4 = w2r[q];
            const double wd0 = (double)w4.x, wd1 = (double)w4.y;
            const double wd2 = (double)w4.z, wd3 = (double)w4.w;
            #pragma unroll
            for (int bt = 0; bt < BT; ++bt) {
                if ((mm[bt][q >> 3] >> ((q & 7) * 4)) & 15u) {   // uniform -> s_cbranch
                    float4 s4 = *reinterpret_cast<const float4*>(&s1s[bt][jbase + q * 4]);
                    double a = acc[bt];
                    a = fma(wd0, (double)s4.x, a);
                    a = fma(wd1, (double)s4.y, a);
                    a = fma(wd2, (double)s4.z, a);
                    a = fma(wd3, (double)s4.w, a);
                    acc[bt] = a;
                }
            }
        }
        if (h) {
            #pragma unroll
            for (int bt = 0; bt < BT; ++bt) redh[bt][n] = acc[bt];
        }
        __syncthreads();

        // ---- LIF layer 2 on h==0 ----
        if (!h) {
            #pragma unroll
            for (int bt = 0; bt < BT; ++bt) {
                const double h2 = acc[bt] + redh[bt][n] + b2d;
                double v = v2r[bt];
                v = v + (h2 - v) * 0.5;
                const bool sp = (v >= 1.0);
                v2r[bt] = sp ? 0.0 : v;
                s2s[bt][n] = sp ? 1.0f : 0.0f;
            }
        }
        __syncthreads();

        // ---- h3 = s2 @ W3^T: 512 threads = 64 tasks x 8 j-chunks ----
        {
            double a3 = 0.0;
            const int j0 = chunk * 32;
            #pragma unroll
            for (int q = 0; q < 8; ++q) {
                float4 w4 = *reinterpret_cast<const float4*>(&w3s[ha][j0 + q * 4]);
                float4 s4 = *reinterpret_cast<const float4*>(&s2s[hbt][j0 + q * 4]);
                a3 = fma((double)w4.x, (double)s4.x, a3);
                a3 = fma((double)w4.y, (double)s4.y, a3);
                a3 = fma((double)w4.z, (double)s4.z, a3);
                a3 = fma((double)w4.w, (double)s4.w, a3);
            }
            red3[chunk][task] = a3;
        }
        __syncthreads();

        // ---- non-spiking integrate on threads 0..63 ----
        if (tid < 64) {
            const double h3 = ((red3[0][task] + red3[1][task]) + (red3[2][task] + red3[3][task]))
                            + ((red3[4][task] + red3[5][task]) + (red3[6][task] + red3[7][task]))
                            + b3d;
            double v = v3r;
            v = v + (h3 - v) * 0.5;
            v3r = v;
        }
    }

    // ---- output: tanh(v3) -> FLOAT32 ----
    if (tid < 64) {
        out[(b0 + hbt) * A_DIM + ha] = (float)tanh(v3r);
    }
}

extern "C" void kernel_launch(void* const* d_in, const int* in_sizes, int n_in,
                              void* d_out, int out_size, void* d_ws, size_t ws_size,
                              hipStream_t stream)
{
    const float* state = (const float*)d_in[0];
    const float* W1    = (const float*)d_in[1];
    const float* b1    = (const float*)d_in[2];
    const float* W2    = (const float*)d_in[3];
    const float* b2    = (const float*)d_in[4];
    const float* W3    = (const float*)d_in[5];
    const float* b3    = (const float*)d_in[6];
    float* out = (float*)d_out;

    const int B = in_sizes[0] / S_DIM;      // 131072
    const int grid = B / BT;                // 16384

    snn_actor_f64<<<grid, 512, 0, stream>>>(state, W1, b1, W2, b2, W3, b3, out);
}

// Round 6
// 24012.720 us; speedup vs baseline: 1.0020x; 1.0011x over previous
//
#include <hip/hip_runtime.h>
#include <hip/hip_bf16.h>

#define S_DIM 128
#define H_DIM 256
#define A_DIM 8
#define T_STEPS 16
#define BT 8            // batch elements per block
#define HP 264          // padded row length for f32 LDS tiles

// 512 threads: tid = (h<<8) | n ; n = neuron 0..255, h = j-half (0..1).
// Each thread holds W2[n][128h .. 128h+128) in 128 VGPRs (32 float4).
// LIF state (h1,v1,v2) lives on h==0 threads. All accumulation in f64 to
// match the float-accurate numpy reference (f32 products are exact in f64).
// OUTPUT IS FLOAT32 (reference returns jnp.float32).
__global__ __launch_bounds__(512, 2)
void snn_actor_f64(const float* __restrict__ state,
                   const float* __restrict__ W1, const float* __restrict__ b1,
                   const float* __restrict__ W2, const float* __restrict__ b2,
                   const float* __restrict__ W3, const float* __restrict__ b3,
                   float* __restrict__ out)
{
    __shared__ alignas(16) float  st[BT][S_DIM];     // 4 KB state tile
    __shared__ alignas(16) float  s1s[BT][HP];       // 8.25 KB spikes L1
    __shared__ alignas(16) float  s2s[BT][HP];       // 8.25 KB spikes L2
    __shared__ alignas(16) float  w3s[A_DIM][HP];    // 8.25 KB W3 staged
    __shared__ double redh[BT][H_DIM];               // 16 KB h2/h1 partials (h==1 half)
    __shared__ double red3[8][64];                   // 4 KB  h3 chunk partials
    __shared__ unsigned int msk[BT][8];              // 256 B spike bitmasks

    const int tid = threadIdx.x;
    const int n   = tid & 255;
    const int h   = tid >> 8;
    const long b0 = (long)blockIdx.x * BT;

    // ---- stage state tile (1024 f32 = 256 float4) ----
    if (tid < 256) {
        reinterpret_cast<float4*>(&st[0][0])[tid] =
            reinterpret_cast<const float4*>(state + b0 * S_DIM)[tid];
    }
    // ---- stage W3 (2048 f32 = 512 float4; one per thread) ----
    {
        const int a = tid >> 6, c = tid & 63;
        reinterpret_cast<float4*>(&w3s[a][0])[c] =
            reinterpret_cast<const float4*>(W3)[tid];
    }
    __syncthreads();

    // ---- W2 half-row into registers (32 float4 = 128 VGPR) ----
    float4 w2r[32];
    {
        const float4* w2p = reinterpret_cast<const float4*>(W2 + n * H_DIM + h * 128);
        #pragma unroll
        for (int q = 0; q < 32; ++q) w2r[q] = w2p[q];
    }

    // ---- h1 = state @ W1^T + b1 in f64, split by k-half ----
    double hacc[BT];
    #pragma unroll
    for (int bt = 0; bt < BT; ++bt) hacc[bt] = 0.0;
    {
        const float* w1p = W1 + n * S_DIM + h * 64;
        for (int kq = 0; kq < 16; ++kq) {
            float4 w4 = reinterpret_cast<const float4*>(w1p)[kq];
            const double wd0 = (double)w4.x, wd1 = (double)w4.y;
            const double wd2 = (double)w4.z, wd3 = (double)w4.w;
            #pragma unroll
            for (int bt = 0; bt < BT; ++bt) {
                float4 s4 = *reinterpret_cast<const float4*>(&st[bt][h * 64 + kq * 4]);
                double a = hacc[bt];
                a = fma(wd0, (double)s4.x, a);
                a = fma(wd1, (double)s4.y, a);
                a = fma(wd2, (double)s4.z, a);
                a = fma(wd3, (double)s4.w, a);
                hacc[bt] = a;
            }
        }
    }
    if (h) {
        #pragma unroll
        for (int bt = 0; bt < BT; ++bt) redh[bt][n] = hacc[bt];
    }
    __syncthreads();

    double h1r[BT], v1r[BT], v2r[BT];
    const double b2d = h ? 0.0 : (double)b2[n];
    if (!h) {
        const double b1d = (double)b1[n];
        #pragma unroll
        for (int bt = 0; bt < BT; ++bt) {
            h1r[bt] = hacc[bt] + redh[bt][n] + b1d;
            v1r[bt] = 0.0;
            v2r[bt] = 0.0;
        }
    } else {
        #pragma unroll
        for (int bt = 0; bt < BT; ++bt) { h1r[bt] = 0.0; v1r[bt] = 0.0; v2r[bt] = 0.0; }
    }

    // h3 task mapping (threads cooperate 8-way over j)
    const int task  = tid & 63;          // (bt,a)
    const int chunk = tid >> 6;          // j-chunk 0..7 (32 j each)
    const int hbt = task >> 3, ha = task & 7;
    const double b3d = (double)b3[ha];
    double v3r = 0.0;

    for (int t = 0; t < T_STEPS; ++t) {
        // ---- LIF layer 1 (h==0 threads own neurons), spikes + bitmask ----
        if (!h) {
            #pragma unroll
            for (int bt = 0; bt < BT; ++bt) {
                double v = v1r[bt];
                v = v + (h1r[bt] - v) * 0.5;
                const bool sp = (v >= 1.0);
                v1r[bt] = sp ? 0.0 : v;
                s1s[bt][n] = sp ? 1.0f : 0.0f;
                unsigned long long bal = __ballot(sp);
                if ((n & 63) == 0) {
                    const int w = n >> 6;
                    msk[bt][2 * w]     = (unsigned int)bal;
                    msk[bt][2 * w + 1] = (unsigned int)(bal >> 32);
                }
            }
        }
        __syncthreads();

        // ---- h2 partial: thread's 128-j half, skip all-zero spike quads ----
        double acc[BT];
        #pragma unroll
        for (int bt = 0; bt < BT; ++bt) acc[bt] = 0.0;

        unsigned int mm[BT][4];
        #pragma unroll
        for (int bt = 0; bt < BT; ++bt) {
            #pragma unroll
            for (int w = 0; w < 4; ++w)
                mm[bt][w] = __builtin_amdgcn_readfirstlane(msk[bt][4 * h + w]);
        }

        const int jbase = h * 128;
        #pragma unroll
        for (int q = 0; q < 32; ++q) {
            const float4 w4 = w2r[q];
            const double wd0 = (double)w4.x, wd1 = (double)w4.y;
            const double wd2 = (double)w4.z, wd3 = (double)w4.w;
            #pragma unroll
            for (int bt = 0; bt < BT; ++bt) {
                if ((mm[bt][q >> 3] >> ((q & 7) * 4)) & 15u) {   // uniform -> s_cbranch
                    float4 s4 = *reinterpret_cast<const float4*>(&s1s[bt][jbase + q * 4]);
                    double a = acc[bt];
                    a = fma(wd0, (double)s4.x, a);
                    a = fma(wd1, (double)s4.y, a);
                    a = fma(wd2, (double)s4.z, a);
                    a = fma(wd3, (double)s4.w, a);
                    acc[bt] = a;
                }
            }
        }
        if (h) {
            #pragma unroll
            for (int bt = 0; bt < BT; ++bt) redh[bt][n] = acc[bt];
        }
        __syncthreads();

        // ---- LIF layer 2 on h==0 ----
        if (!h) {
            #pragma unroll
            for (int bt = 0; bt < BT; ++bt) {
                const double h2 = acc[bt] + redh[bt][n] + b2d;
                double v = v2r[bt];
                v = v + (h2 - v) * 0.5;
                const bool sp = (v >= 1.0);
                v2r[bt] = sp ? 0.0 : v;
                s2s[bt][n] = sp ? 1.0f : 0.0f;
            }
        }
        __syncthreads();

        // ---- h3 = s2 @ W3^T: 512 threads = 64 tasks x 8 j-chunks ----
        {
            double a3 = 0.0;
            const int j0 = chunk * 32;
            #pragma unroll
            for (int q = 0; q < 8; ++q) {
                float4 w4 = *reinterpret_cast<const float4*>(&w3s[ha][j0 + q * 4]);
                float4 s4 = *reinterpret_cast<const float4*>(&s2s[hbt][j0 + q * 4]);
                a3 = fma((double)w4.x, (double)s4.x, a3);
                a3 = fma((double)w4.y, (double)s4.y, a3);
                a3 = fma((double)w4.z, (double)s4.z, a3);
                a3 = fma((double)w4.w, (double)s4.w, a3);
            }
            red3[chunk][task] = a3;
        }
        __syncthreads();

        // ---- non-spiking integrate on threads 0..63 ----
        if (tid < 64) {
            const double h3 = ((red3[0][task] + red3[1][task]) + (red3[2][task] + red3[3][task]))
                            + ((red3[4][task] + red3[5][task]) + (red3[6][task] + red3[7][task]))
                            + b3d;
            double v = v3r;
            v = v + (h3 - v) * 0.5;
            v3r = v;
        }
    }

    // ---- output: tanh(v3) -> FLOAT32 ----
    if (tid < 64) {
        out[(b0 + hbt) * A_DIM + ha] = (float)tanh(v3r);
    }
}

extern "C" void kernel_launch(void* const* d_in, const int* in_sizes, int n_in,
                              void* d_out, int out_size, void* d_ws, size_t ws_size,
                              hipStream_t stream)
{
    const float* state = (const float*)d_in[0];
    const float* W1    = (const float*)d_in[1];
    const float* b1    = (const float*)d_in[2];
    const float* W2    = (const float*)d_in[3];
    const float* b2    = (const float*)d_in[4];
    const float* W3    = (const float*)d_in[5];
    const float* b3    = (const float*)d_in[6];
    float* out = (float*)d_out;

    const int B = in_sizes[0] / S_DIM;      // 131072
    const int grid = B / BT;                // 16384

    snn_actor_f64<<<grid, 512, 0, stream>>>(state, W1, b1, W2, b2, W3, b3, out);
}

// Round 7
// 10127.973 us; speedup vs baseline: 2.3756x; 2.3709x over previous
//
#include <hip/hip_runtime.h>
#include <hip/hip_bf16.h>
#include <math.h>

#define S_DIM 128
#define H_DIM 256
#define A_DIM 8
#define T_STEPS 16
#define HP 264
#define EPS_FLAG 4e-6

// ============== main kernel: f32 fast h2 + exact f64 LIF + flagging ==========
// 512 threads: tid = (h<<8)|n ; n = neuron, h = j-half. BTM batch elems/block.
// Layer-1 LIF fully f64 (exact). h2 via f32 per-quad sums accumulated in f64,
// W2 streamed from L2 (no register tile -> no spill). v2 recursion f64; any
// decision within EPS_FLAG of threshold flags the batch element for fixup.
#define BTM 16
__global__ __launch_bounds__(512, 2)
void snn_main(const float* __restrict__ state,
              const float* __restrict__ W1, const float* __restrict__ b1,
              const float* __restrict__ W2, const float* __restrict__ b2,
              const float* __restrict__ W3, const float* __restrict__ b3,
              float* __restrict__ out, unsigned char* __restrict__ flags)
{
    __shared__ alignas(16) float st[BTM][S_DIM];        // 8 KB
    __shared__ alignas(16) float s1s[BTM][HP];          // 16.5 KB
    __shared__ alignas(16) float s2s[BTM][HP];          // 16.5 KB
    __shared__ alignas(16) float w3s[A_DIM][HP];        // 8.25 KB
    __shared__ double redh[BTM][H_DIM];                 // 32 KB
    __shared__ double red3[4][BTM * A_DIM];             // 4 KB
    __shared__ unsigned int msk[BTM][8];
    __shared__ unsigned int flagw;

    const int tid = threadIdx.x;
    const int n = tid & 255;
    const int h = tid >> 8;
    const long b0 = (long)blockIdx.x * BTM;

    if (tid == 0) flagw = 0;

    // stage state tile: BTM*128 = 2048 f32 = 512 float4 (one per thread)
    reinterpret_cast<float4*>(&st[0][0])[tid] =
        reinterpret_cast<const float4*>(state + b0 * S_DIM)[tid];
    // stage W3: 2048 f32 = 512 float4
    {
        const int a = tid >> 6, c = tid & 63;
        reinterpret_cast<float4*>(&w3s[a][0])[c] =
            reinterpret_cast<const float4*>(W3)[tid];
    }
    __syncthreads();

    // ---- h1 = state @ W1^T + b1 exact f64, split by k-half ----
    double hacc[BTM];
    #pragma unroll
    for (int bt = 0; bt < BTM; ++bt) hacc[bt] = 0.0;
    {
        const float* w1p = W1 + n * S_DIM + h * 64;
        #pragma unroll 4
        for (int kq = 0; kq < 16; ++kq) {
            const float4 w4 = reinterpret_cast<const float4*>(w1p)[kq];
            const double wd0 = (double)w4.x, wd1 = (double)w4.y;
            const double wd2 = (double)w4.z, wd3 = (double)w4.w;
            #pragma unroll
            for (int bt = 0; bt < BTM; ++bt) {
                const float4 s4 = *reinterpret_cast<const float4*>(&st[bt][h * 64 + kq * 4]);
                double a = hacc[bt];
                a = fma(wd0, (double)s4.x, a);
                a = fma(wd1, (double)s4.y, a);
                a = fma(wd2, (double)s4.z, a);
                a = fma(wd3, (double)s4.w, a);
                hacc[bt] = a;
            }
        }
    }
    if (h) {
        #pragma unroll
        for (int bt = 0; bt < BTM; ++bt) redh[bt][n] = hacc[bt];
    }
    __syncthreads();

    double h1d[BTM], v1d[BTM], v2d[BTM];
    if (!h) {
        const double b1d = (double)b1[n];
        #pragma unroll
        for (int bt = 0; bt < BTM; ++bt) {
            h1d[bt] = hacc[bt] + redh[bt][n] + b1d;
            v1d[bt] = 0.0; v2d[bt] = 0.0;
        }
    } else {
        #pragma unroll
        for (int bt = 0; bt < BTM; ++bt) { h1d[bt] = 0.0; v1d[bt] = 0.0; v2d[bt] = 0.0; }
    }
    const double b2d = (!h) ? (double)b2[n] : 0.0;

    const float* w2p = W2 + n * H_DIM + h * 128;
    const int task = tid & 127, chunk = tid >> 7;   // h3: 128 tasks x 4 chunks
    const int obt = task >> 3, oa = task & 7;
    const double b3d = (double)b3[oa];
    double v3r = 0.0;
    unsigned int flreg = 0;

    for (int t = 0; t < T_STEPS; ++t) {
        // ---- LIF1 exact f64 (h==0 threads own neurons) ----
        if (!h) {
            #pragma unroll
            for (int bt = 0; bt < BTM; ++bt) {
                double v = v1d[bt];
                v = v + (h1d[bt] - v) * 0.5;
                const bool sp = (v >= 1.0);
                v1d[bt] = sp ? 0.0 : v;
                s1s[bt][n] = sp ? 1.0f : 0.0f;
                const unsigned long long bal = __ballot(sp);
                if ((n & 63) == 0) {
                    const int w = n >> 6;
                    msk[bt][2 * w]     = (unsigned int)bal;
                    msk[bt][2 * w + 1] = (unsigned int)(bal >> 32);
                }
            }
        }
        __syncthreads();

        // ---- h2 fast path: stream W2 half-row, f32 quad sums -> f64 acc ----
        double accd[BTM];
        #pragma unroll
        for (int bt = 0; bt < BTM; ++bt) accd[bt] = 0.0;

        #pragma unroll 1
        for (int oct = 0; oct < 4; ++oct) {
            unsigned int mw[BTM];
            #pragma unroll
            for (int bt = 0; bt < BTM; ++bt)
                mw[bt] = __builtin_amdgcn_readfirstlane(msk[bt][4 * h + oct]);
            #pragma unroll
            for (int qq = 0; qq < 8; ++qq) {
                const int q = oct * 8 + qq;
                const float4 w4 = reinterpret_cast<const float4*>(w2p)[q];
                #pragma unroll
                for (int bt = 0; bt < BTM; ++bt) {
                    if ((mw[bt] >> (qq * 4)) & 15u) {    // uniform -> s_cbranch
                        const float4 s4 = *reinterpret_cast<const float4*>(&s1s[bt][h * 128 + q * 4]);
                        float qs = w4.x * s4.x;
                        qs = fmaf(w4.y, s4.y, qs);
                        qs = fmaf(w4.z, s4.z, qs);
                        qs = fmaf(w4.w, s4.w, qs);
                        accd[bt] += (double)qs;
                    }
                }
            }
        }
        if (h) {
            #pragma unroll
            for (int bt = 0; bt < BTM; ++bt) redh[bt][n] = accd[bt];
        }
        __syncthreads();

        // ---- LIF2: exact f64 recursion with approx h2 + flag band ----
        if (!h) {
            #pragma unroll
            for (int bt = 0; bt < BTM; ++bt) {
                const double h2 = accd[bt] + redh[bt][n] + b2d;
                double v = v2d[bt];
                v = v + (h2 - v) * 0.5;
                if (fabs(v - 1.0) < EPS_FLAG) flreg |= (1u << bt);
                const bool sp = (v >= 1.0);
                v2d[bt] = sp ? 0.0 : v;
                s2s[bt][n] = sp ? 1.0f : 0.0f;
            }
        }
        __syncthreads();

        // ---- h3 exact f64: 128 tasks (bt,a) x 4 chunks of 64 j ----
        {
            double a3 = 0.0;
            const int j0 = chunk * 64;
            #pragma unroll
            for (int qq = 0; qq < 16; ++qq) {
                const float4 w4 = *reinterpret_cast<const float4*>(&w3s[oa][j0 + qq * 4]);
                const float4 s4 = *reinterpret_cast<const float4*>(&s2s[obt][j0 + qq * 4]);
                a3 = fma((double)w4.x, (double)s4.x, a3);
                a3 = fma((double)w4.y, (double)s4.y, a3);
                a3 = fma((double)w4.z, (double)s4.z, a3);
                a3 = fma((double)w4.w, (double)s4.w, a3);
            }
            red3[chunk][task] = a3;
        }
        __syncthreads();
        if (tid < 128) {
            const double h3 = ((red3[0][task] + red3[1][task])
                             + (red3[2][task] + red3[3][task])) + b3d;
            v3r = v3r + (h3 - v3r) * 0.5;
        }
    }

    if (flreg) atomicOr(&flagw, flreg);
    if (tid < 128) out[(b0 + obt) * A_DIM + oa] = (float)tanh(v3r);
    __syncthreads();
    if (tid < BTM) flags[b0 + tid] = (unsigned char)((flagw >> tid) & 1u);
}

// ============== fixup kernel: full f64 re-sim of flagged batch elems =========
// Streaming-W2 variant of the validated R6 kernel (no register W2 tile).
#define BTF 8
__global__ __launch_bounds__(512, 2)
void snn_fix(const float* __restrict__ state,
             const float* __restrict__ W1, const float* __restrict__ b1,
             const float* __restrict__ W2, const float* __restrict__ b2,
             const float* __restrict__ W3, const float* __restrict__ b3,
             float* __restrict__ out, const unsigned char* __restrict__ flags)
{
    __shared__ alignas(16) float st[BTF][S_DIM];
    __shared__ alignas(16) float s1s[BTF][HP];
    __shared__ alignas(16) float s2s[BTF][HP];
    __shared__ alignas(16) float w3s[A_DIM][HP];
    __shared__ double redh[BTF][H_DIM];
    __shared__ double red3[8][64];
    __shared__ unsigned int msk[BTF][8];
    __shared__ unsigned int anyf;

    const int tid = threadIdx.x;
    const int n = tid & 255;
    const int h = tid >> 8;
    const long b0 = (long)blockIdx.x * BTF;

    if (tid == 0) anyf = 0;
    __syncthreads();
    if (tid < BTF && flags[b0 + tid]) atomicOr(&anyf, 1u);
    __syncthreads();
    if (!anyf) return;

    if (tid < 256) {
        reinterpret_cast<float4*>(&st[0][0])[tid] =
            reinterpret_cast<const float4*>(state + b0 * S_DIM)[tid];
    }
    {
        const int a = tid >> 6, c = tid & 63;
        reinterpret_cast<float4*>(&w3s[a][0])[c] =
            reinterpret_cast<const float4*>(W3)[tid];
    }
    __syncthreads();

    // h1 exact f64
    double hacc[BTF];
    #pragma unroll
    for (int bt = 0; bt < BTF; ++bt) hacc[bt] = 0.0;
    {
        const float* w1p = W1 + n * S_DIM + h * 64;
        #pragma unroll 4
        for (int kq = 0; kq < 16; ++kq) {
            const float4 w4 = reinterpret_cast<const float4*>(w1p)[kq];
            const double wd0 = (double)w4.x, wd1 = (double)w4.y;
            const double wd2 = (double)w4.z, wd3 = (double)w4.w;
            #pragma unroll
            for (int bt = 0; bt < BTF; ++bt) {
                const float4 s4 = *reinterpret_cast<const float4*>(&st[bt][h * 64 + kq * 4]);
                double a = hacc[bt];
                a = fma(wd0, (double)s4.x, a);
                a = fma(wd1, (double)s4.y, a);
                a = fma(wd2, (double)s4.z, a);
                a = fma(wd3, (double)s4.w, a);
                hacc[bt] = a;
            }
        }
    }
    if (h) {
        #pragma unroll
        for (int bt = 0; bt < BTF; ++bt) redh[bt][n] = hacc[bt];
    }
    __syncthreads();

    double h1r[BTF], v1r[BTF], v2r[BTF];
    if (!h) {
        const double b1d = (double)b1[n];
        #pragma unroll
        for (int bt = 0; bt < BTF; ++bt) {
            h1r[bt] = hacc[bt] + redh[bt][n] + b1d;
            v1r[bt] = 0.0; v2r[bt] = 0.0;
        }
    } else {
        #pragma unroll
        for (int bt = 0; bt < BTF; ++bt) { h1r[bt] = 0.0; v1r[bt] = 0.0; v2r[bt] = 0.0; }
    }
    const double b2d = (!h) ? (double)b2[n] : 0.0;

    const float* w2p = W2 + n * H_DIM + h * 128;
    const int task = tid & 63, chunk = tid >> 6;
    const int hbt = task >> 3, ha = task & 7;
    const double b3d = (double)b3[ha];
    double v3r = 0.0;

    for (int t = 0; t < T_STEPS; ++t) {
        if (!h) {
            #pragma unroll
            for (int bt = 0; bt < BTF; ++bt) {
                double v = v1r[bt];
                v = v + (h1r[bt] - v) * 0.5;
                const bool sp = (v >= 1.0);
                v1r[bt] = sp ? 0.0 : v;
                s1s[bt][n] = sp ? 1.0f : 0.0f;
                const unsigned long long bal = __ballot(sp);
                if ((n & 63) == 0) {
                    const int w = n >> 6;
                    msk[bt][2 * w]     = (unsigned int)bal;
                    msk[bt][2 * w + 1] = (unsigned int)(bal >> 32);
                }
            }
        }
        __syncthreads();

        // h2 exact: f64 FMA over streamed W2 quads, per-bt nibble skip
        double acc[BTF];
        #pragma unroll
        for (int bt = 0; bt < BTF; ++bt) acc[bt] = 0.0;

        #pragma unroll 1
        for (int oct = 0; oct < 4; ++oct) {
            unsigned int mw[BTF];
            #pragma unroll
            for (int bt = 0; bt < BTF; ++bt)
                mw[bt] = __builtin_amdgcn_readfirstlane(msk[bt][4 * h + oct]);
            #pragma unroll
            for (int qq = 0; qq < 8; ++qq) {
                const int q = oct * 8 + qq;
                const float4 w4 = reinterpret_cast<const float4*>(w2p)[q];
                const double wd0 = (double)w4.x, wd1 = (double)w4.y;
                const double wd2 = (double)w4.z, wd3 = (double)w4.w;
                #pragma unroll
                for (int bt = 0; bt < BTF; ++bt) {
                    if ((mw[bt] >> (qq * 4)) & 15u) {
                        const float4 s4 = *reinterpret_cast<const float4*>(&s1s[bt][h * 128 + q * 4]);
                        double a = acc[bt];
                        a = fma(wd0, (double)s4.x, a);
                        a = fma(wd1, (double)s4.y, a);
                        a = fma(wd2, (double)s4.z, a);
                        a = fma(wd3, (double)s4.w, a);
                        acc[bt] = a;
                    }
                }
            }
        }
        if (h) {
            #pragma unroll
            for (int bt = 0; bt < BTF; ++bt) redh[bt][n] = acc[bt];
        }
        __syncthreads();

        if (!h) {
            #pragma unroll
            for (int bt = 0; bt < BTF; ++bt) {
                const double h2 = acc[bt] + redh[bt][n] + b2d;
                double v = v2r[bt];
                v = v + (h2 - v) * 0.5;
                const bool sp = (v >= 1.0);
                v2r[bt] = sp ? 0.0 : v;
                s2s[bt][n] = sp ? 1.0f : 0.0f;
            }
        }
        __syncthreads();

        {
            double a3 = 0.0;
            const int j0 = chunk * 32;
            #pragma unroll
            for (int qq = 0; qq < 8; ++qq) {
                const float4 w4 = *reinterpret_cast<const float4*>(&w3s[ha][j0 + qq * 4]);
                const float4 s4 = *reinterpret_cast<const float4*>(&s2s[hbt][j0 + qq * 4]);
                a3 = fma((double)w4.x, (double)s4.x, a3);
                a3 = fma((double)w4.y, (double)s4.y, a3);
                a3 = fma((double)w4.z, (double)s4.z, a3);
                a3 = fma((double)w4.w, (double)s4.w, a3);
            }
            red3[chunk][task] = a3;
        }
        __syncthreads();

        if (tid < 64) {
            const double h3 = ((red3[0][task] + red3[1][task]) + (red3[2][task] + red3[3][task]))
                            + ((red3[4][task] + red3[5][task]) + (red3[6][task] + red3[7][task]))
                            + b3d;
            v3r = v3r + (h3 - v3r) * 0.5;
        }
    }

    if (tid < 64) {
        out[(b0 + hbt) * A_DIM + ha] = (float)tanh(v3r);
    }
}

extern "C" void kernel_launch(void* const* d_in, const int* in_sizes, int n_in,
                              void* d_out, int out_size, void* d_ws, size_t ws_size,
                              hipStream_t stream)
{
    const float* state = (const float*)d_in[0];
    const float* W1    = (const float*)d_in[1];
    const float* b1    = (const float*)d_in[2];
    const float* W2    = (const float*)d_in[3];
    const float* b2    = (const float*)d_in[4];
    const float* W3    = (const float*)d_in[5];
    const float* b3    = (const float*)d_in[6];
    float* out = (float*)d_out;
    unsigned char* flags = (unsigned char*)d_ws;

    const int B = in_sizes[0] / S_DIM;      // 131072

    snn_main<<<B / BTM, 512, 0, stream>>>(state, W1, b1, W2, b2, W3, b3, out, flags);
    snn_fix <<<B / BTF, 512, 0, stream>>>(state, W1, b1, W2, b2, W3, b3, out, flags);
}

// Round 8
// 1765.079 us; speedup vs baseline: 13.6309x; 5.7380x over previous
//
#include <hip/hip_runtime.h>
#include <hip/hip_bf16.h>
#include <math.h>

#define S_DIM 128
#define H_DIM 256
#define A_DIM 8
#define T_STEPS 16
#define BTW 16              // batch elements per block (main)
#define EPS_BAND 2e-4f      // flag band around spike threshold (>> 1e-4 worst-case h2 err)

typedef __attribute__((ext_vector_type(8))) short short8;
typedef __attribute__((ext_vector_type(4))) float f32x4;

__device__ inline unsigned short f32_to_bf16_rn(float f) {
    unsigned int u = __float_as_uint(f);
    return (unsigned short)((u + 0x7FFFu + ((u >> 16) & 1u)) >> 16);
}
__device__ inline float bf16_bits_to_f32(unsigned short b) {
    return __uint_as_float(((unsigned int)b) << 16);
}

// ================= main kernel: MFMA bf16x2 fast path + flag band ============
// 512 threads = 8 waves. Wave w owns N-tiles {2w, 2w+1} (16 neurons each).
// A (spikes) 16x32 frags from swizzled LDS; B (W2 hi/mid bf16) register-resident.
// LIF1 exact: h1 in f64 once -> per-(b,n) 16-bit spike pattern. LIF2 in f32 with
// flag band; u[n] = sum_t 2^(t-16) s2_t[n] (exact) kills the per-t h3 matmul.
__global__ __launch_bounds__(512, 2)
void snn_mfma(const float* __restrict__ state,
              const float* __restrict__ W1, const float* __restrict__ b1,
              const float* __restrict__ W2, const float* __restrict__ b2,
              const float* __restrict__ W3, const float* __restrict__ b3,
              float* __restrict__ out,
              unsigned int* __restrict__ gcount, unsigned int* __restrict__ glist,
              unsigned int listcap)
{
    __shared__ float lds_f[BTW * 260];          // st [16][128] (phase 1) / u [16][260] (phase 3)
    __shared__ unsigned short s1t[BTW * 256];   // spike tile bf16, XOR-swizzled
    __shared__ float w3s[A_DIM * 260];          // W3 staged, padded rows
    __shared__ unsigned int flagw;

    const int tid = threadIdx.x;
    const int l   = tid & 63;
    const int w   = tid >> 6;
    const int cl  = l & 15;        // MFMA row (A) / col (B)
    const int c8  = l >> 4;        // k-chunk 0..3
    const long b0 = (long)blockIdx.x * BTW;

    if (tid == 0) flagw = 0;

    // ---- stage state tile [16][128] (512 float4) ----
    {
        const float4 v = reinterpret_cast<const float4*>(state + b0 * S_DIM)[tid];
        const int b = tid >> 5, k = (tid & 31) * 4;
        *reinterpret_cast<float4*>(&lds_f[b * S_DIM + k]) = v;
    }
    // ---- stage W3 [8][260] ----
    {
        const int a = tid >> 6, c = tid & 63;
        const float4 v = reinterpret_cast<const float4*>(W3)[tid];
        *reinterpret_cast<float4*>(&w3s[a * 260 + c * 4]) = v;
    }

    // ---- W2 B-fragments: hi/mid bf16 split, register-resident ----
    short8 bhi[2][8], bmid[2][8];
    #pragma unroll
    for (int nt = 0; nt < 2; ++nt) {
        const int n = w * 32 + nt * 16 + cl;
        #pragma unroll
        for (int ks = 0; ks < 8; ++ks) {
            const float* src = W2 + n * H_DIM + ks * 32 + c8 * 8;
            const float4 a0 = *reinterpret_cast<const float4*>(src);
            const float4 a1 = *reinterpret_cast<const float4*>(src + 4);
            const float wv[8] = {a0.x, a0.y, a0.z, a0.w, a1.x, a1.y, a1.z, a1.w};
            short8 hi8, mi8;
            #pragma unroll
            for (int e = 0; e < 8; ++e) {
                const unsigned short hb = f32_to_bf16_rn(wv[e]);
                const float rem = wv[e] - bf16_bits_to_f32(hb);   // exact (Sterbenz)
                hi8[e] = (short)hb;
                mi8[e] = (short)f32_to_bf16_rn(rem);
            }
            bhi[nt][ks] = hi8;
            bmid[nt][ks] = mi8;
        }
    }
    const float b2v0 = b2[w * 32 + cl];
    const float b2v1 = b2[w * 32 + 16 + cl];
    __syncthreads();

    // ---- h1 exact f64 + 16-step L1 pattern per (b,n) ----
    const int n1 = tid & 255;     // owned neuron
    const int bh = tid >> 8;      // b-half (8 b's each)
    unsigned int pat[4] = {0, 0, 0, 0};   // 8 x u16 patterns packed
    {
        double acc[8];
        #pragma unroll
        for (int i = 0; i < 8; ++i) acc[i] = 0.0;
        const float* w1p = W1 + n1 * S_DIM;
        for (int kq = 0; kq < 32; ++kq) {
            const float4 w4 = reinterpret_cast<const float4*>(w1p)[kq];
            const double wd0 = (double)w4.x, wd1 = (double)w4.y;
            const double wd2 = (double)w4.z, wd3 = (double)w4.w;
            #pragma unroll
            for (int b8 = 0; b8 < 8; ++b8) {
                const float4 s4 = *reinterpret_cast<const float4*>(
                    &lds_f[(bh * 8 + b8) * S_DIM + kq * 4]);
                double a = acc[b8];
                a = fma(wd0, (double)s4.x, a);
                a = fma(wd1, (double)s4.y, a);
                a = fma(wd2, (double)s4.z, a);
                a = fma(wd3, (double)s4.w, a);
                acc[b8] = a;
            }
        }
        const double b1d = (double)b1[n1];
        #pragma unroll
        for (int b8 = 0; b8 < 8; ++b8) {
            const double h1 = acc[b8] + b1d;
            double v = 0.0;
            unsigned int p = 0;
            for (int t = 0; t < T_STEPS; ++t) {
                v = v + (h1 - v) * 0.5;
                if (v >= 1.0) { p |= (1u << t); v = 0.0; }
            }
            pat[b8 >> 1] |= p << ((b8 & 1) * 16);
        }
    }

    // ---- t-loop: spikes -> MFMA h2 -> LIF2 (+u, +flag) ----
    f32x4 v2a = {0, 0, 0, 0}, v2b = {0, 0, 0, 0};
    f32x4 ua = {0, 0, 0, 0}, ub = {0, 0, 0, 0};
    unsigned int fl = 0;
    float ct = 0x1p-16f;

    #pragma unroll 1
    for (int t = 0; t < T_STEPS; ++t) {
        #pragma unroll
        for (int b8 = 0; b8 < 8; ++b8) {
            const int b = bh * 8 + b8;
            const unsigned int bit = (pat[b8 >> 1] >> ((b8 & 1) * 16 + t)) & 1u;
            s1t[b * 256 + (n1 ^ ((b & 7) << 3))] =
                bit ? (unsigned short)0x3F80 : (unsigned short)0;
        }
        __syncthreads();

        f32x4 acc0 = {0, 0, 0, 0}, acc1 = {0, 0, 0, 0};
        #pragma unroll
        for (int ks = 0; ks < 8; ++ks) {
            const int j0 = ks * 32 + c8 * 8;
            const short8 af = *reinterpret_cast<const short8*>(
                &s1t[cl * 256 + (j0 ^ ((cl & 7) << 3))]);
            acc0 = __builtin_amdgcn_mfma_f32_16x16x32_bf16(af, bhi[0][ks], acc0, 0, 0, 0);
            acc1 = __builtin_amdgcn_mfma_f32_16x16x32_bf16(af, bhi[1][ks], acc1, 0, 0, 0);
            acc0 = __builtin_amdgcn_mfma_f32_16x16x32_bf16(af, bmid[0][ks], acc0, 0, 0, 0);
            acc1 = __builtin_amdgcn_mfma_f32_16x16x32_bf16(af, bmid[1][ks], acc1, 0, 0, 0);
        }
        __syncthreads();   // A-reads done before next-t spike writes

        #pragma unroll
        for (int r = 0; r < 4; ++r) {
            {
                const float h2 = acc0[r] + b2v0;
                float v = (v2a[r] + h2) * 0.5f;
                if (fabsf(v - 1.0f) < EPS_BAND) fl |= 1u << r;
                const bool sp = v >= 1.0f;
                v2a[r] = sp ? 0.0f : v;
                ua[r] += sp ? ct : 0.0f;
            }
            {
                const float h2 = acc1[r] + b2v1;
                float v = (v2b[r] + h2) * 0.5f;
                if (fabsf(v - 1.0f) < EPS_BAND) fl |= 1u << r;
                const bool sp = v >= 1.0f;
                v2b[r] = sp ? 0.0f : v;
                ub[r] += sp ? ct : 0.0f;
            }
        }
        ct *= 2.0f;
    }

    if (fl) atomicOr(&flagw, fl << (c8 * 4));

    // ---- dump u [16][260] ----
    #pragma unroll
    for (int r = 0; r < 4; ++r) {
        const int b = c8 * 4 + r;
        lds_f[b * 260 + w * 32 + cl]      = ua[r];
        lds_f[b * 260 + w * 32 + 16 + cl] = ub[r];
    }
    __syncthreads();

    // ---- final: out = tanh(u @ W3^T + b3*(1-2^-16)) ----
    if (tid < BTW * A_DIM) {
        const int b = tid >> 3, a = tid & 7;
        float s0 = 0, s1v = 0, s2v = 0, s3 = 0;
        #pragma unroll 8
        for (int kq = 0; kq < 64; ++kq) {
            const float4 uv = *reinterpret_cast<const float4*>(&lds_f[b * 260 + kq * 4]);
            const float4 wv = *reinterpret_cast<const float4*>(&w3s[a * 260 + kq * 4]);
            s0 = fmaf(uv.x, wv.x, s0);
            s1v = fmaf(uv.y, wv.y, s1v);
            s2v = fmaf(uv.z, wv.z, s2v);
            s3 = fmaf(uv.w, wv.w, s3);
        }
        const float v3 = (s0 + s1v) + (s2v + s3) + b3[a] * (1.0f - 0x1p-16f);
        out[(b0 + b) * A_DIM + a] = tanhf(v3);
    }

    // ---- append flagged batch elems (deduped per block) ----
    if (tid < BTW) {
        if ((flagw >> tid) & 1u) {
            const unsigned int idx = atomicAdd(gcount, 1u);
            if (idx < listcap) glist[idx] = (unsigned int)(b0 + tid);
        }
    }
}

// ================ fixup: exact f64 re-sim of flagged elems ===================
// 512 threads = (n 0..255) x (k-half). One batch elem per grid-stride step.
__global__ __launch_bounds__(512, 2)
void snn_fix(const float* __restrict__ state,
             const float* __restrict__ W1, const float* __restrict__ b1,
             const float* __restrict__ W2, const float* __restrict__ b2,
             const float* __restrict__ W3, const float* __restrict__ b3,
             float* __restrict__ out,
             const unsigned int* __restrict__ gcount,
             const unsigned int* __restrict__ glist,
             unsigned int listcap)
{
    __shared__ float  s1s[H_DIM];
    __shared__ double redh[H_DIM];
    __shared__ double uu[H_DIM];

    const int tid = threadIdx.x;
    const int n = tid & 255;
    const int kh = tid >> 8;
    unsigned int cnt = *gcount;
    if (cnt > listcap) cnt = listcap;
    if (cnt == 0) return;

    float4 w2f[32];
    #pragma unroll
    for (int q = 0; q < 32; ++q)
        w2f[q] = reinterpret_cast<const float4*>(W2 + n * H_DIM + kh * 128)[q];

    const double b1d = (double)b1[n];
    const double b2d = (double)b2[n];

    for (unsigned int i = blockIdx.x; i < cnt; i += gridDim.x) {
        const long be = (long)glist[i];

        double hp = 0.0;
        {
            const float* w1p = W1 + n * S_DIM + kh * 64;
            const float* stp = state + be * S_DIM + kh * 64;
            #pragma unroll
            for (int kq = 0; kq < 16; ++kq) {
                const float4 w4 = reinterpret_cast<const float4*>(w1p)[kq];
                const float4 s4 = reinterpret_cast<const float4*>(stp)[kq];
                hp = fma((double)w4.x, (double)s4.x, hp);
                hp = fma((double)w4.y, (double)s4.y, hp);
                hp = fma((double)w4.z, (double)s4.z, hp);
                hp = fma((double)w4.w, (double)s4.w, hp);
            }
        }
        if (kh) redh[n] = hp;
        __syncthreads();
        double h1 = 0.0, v1 = 0.0, v2 = 0.0, un = 0.0;
        if (!kh) h1 = hp + redh[n] + b1d;
        double ct = 0x1p-16;

        for (int t = 0; t < T_STEPS; ++t) {
            if (!kh) {
                v1 = v1 + (h1 - v1) * 0.5;
                const bool sp = (v1 >= 1.0);
                v1 = sp ? 0.0 : v1;
                s1s[n] = sp ? 1.0f : 0.0f;
            }
            __syncthreads();
            double h2p = 0.0;
            #pragma unroll
            for (int q = 0; q < 32; ++q) {
                const float4 w4 = w2f[q];
                const float4 s4 = *reinterpret_cast<const float4*>(&s1s[kh * 128 + q * 4]);
                h2p = fma((double)w4.x, (double)s4.x, h2p);
                h2p = fma((double)w4.y, (double)s4.y, h2p);
                h2p = fma((double)w4.z, (double)s4.z, h2p);
                h2p = fma((double)w4.w, (double)s4.w, h2p);
            }
            __syncthreads();
            if (kh) redh[n] = h2p;
            __syncthreads();
            if (!kh) {
                const double h2 = h2p + redh[n] + b2d;
                v2 = v2 + (h2 - v2) * 0.5;
                const bool sp = (v2 >= 1.0);
                v2 = sp ? 0.0 : v2;
                un += sp ? ct : 0.0;
            }
            ct *= 2.0;
        }
        if (!kh) uu[n] = un;
        __syncthreads();
        if (tid < A_DIM) {
            double d0 = 0, d1 = 0, d2 = 0, d3 = 0;
            const float* w3p = W3 + tid * H_DIM;
            for (int j = 0; j < H_DIM; j += 4) {
                d0 = fma((double)w3p[j],     uu[j],     d0);
                d1 = fma((double)w3p[j + 1], uu[j + 1], d1);
                d2 = fma((double)w3p[j + 2], uu[j + 2], d2);
                d3 = fma((double)w3p[j + 3], uu[j + 3], d3);
            }
            const double v3 = (d0 + d1) + (d2 + d3) + (double)b3[tid] * (1.0 - 0x1p-16);
            out[be * A_DIM + tid] = (float)tanh(v3);
        }
        __syncthreads();
    }
}

extern "C" void kernel_launch(void* const* d_in, const int* in_sizes, int n_in,
                              void* d_out, int out_size, void* d_ws, size_t ws_size,
                              hipStream_t stream)
{
    const float* state = (const float*)d_in[0];
    const float* W1    = (const float*)d_in[1];
    const float* b1    = (const float*)d_in[2];
    const float* W2    = (const float*)d_in[3];
    const float* b2    = (const float*)d_in[4];
    const float* W3    = (const float*)d_in[5];
    const float* b3    = (const float*)d_in[6];
    float* out = (float*)d_out;

    unsigned int* gcount = (unsigned int*)d_ws;
    unsigned int* glist  = (unsigned int*)d_ws + 4;
    const unsigned int listcap =
        (ws_size > 64) ? (unsigned int)((ws_size - 16) / 4) : 0;

    hipMemsetAsync(d_ws, 0, 16, stream);   // zero flag counter (stream-ordered, capture-safe)

    const int B = in_sizes[0] / S_DIM;     // 131072

    snn_mfma<<<B / BTW, 512, 0, stream>>>(state, W1, b1, W2, b2, W3, b3,
                                          out, gcount, glist, listcap);
    snn_fix<<<2048, 512, 0, stream>>>(state, W1, b1, W2, b2, W3, b3,
                                      out, gcount, glist, listcap);
}